// Round 1
// baseline (561.165 us; speedup 1.0000x reference)
//
#include <hip/hip_runtime.h>
#include <cstdint>
#include <cstddef>

#define DF 128      // feature dim
#define HATT 64     // attention hidden dim

static inline int divup(int a, int b) { return (a + b - 1) / b; }

// ---------------- graph prep ----------------

__global__ __launch_bounds__(256) void hist_kernel(const int* __restrict__ row,
                                                   int* __restrict__ cnt, int E) {
    int i = blockIdx.x * blockDim.x + threadIdx.x;
    int stride = gridDim.x * blockDim.x;
    for (; i < E; i += stride) atomicAdd(&cnt[row[i]], 1);
}

// single block, 1024 threads: exclusive scan of cnt -> row_ptr, copy to cur
__global__ __launch_bounds__(1024) void scan_kernel(const int* __restrict__ cnt,
                                                    int* __restrict__ row_ptr,
                                                    int* __restrict__ cur, int n) {
    __shared__ int sums[1024];
    int t = threadIdx.x;
    int chunk = (n + 1023) >> 10;
    int start = t * chunk;
    int s = 0;
    for (int j = 0; j < chunk; ++j) {
        int idx = start + j;
        if (idx < n) s += cnt[idx];
    }
    sums[t] = s;
    __syncthreads();
    for (int off = 1; off < 1024; off <<= 1) {
        int v = (t >= off) ? sums[t - off] : 0;
        __syncthreads();
        sums[t] += v;
        __syncthreads();
    }
    int run = sums[t] - s;  // exclusive prefix
    for (int j = 0; j < chunk; ++j) {
        int idx = start + j;
        if (idx < n) {
            row_ptr[idx] = run;
            cur[idx] = run;
            run += cnt[idx];
        }
    }
    if (t == 1023) row_ptr[n] = sums[1023];
}

__global__ __launch_bounds__(256) void scatter_kernel(const int* __restrict__ row,
                                                      const int* __restrict__ col,
                                                      int* __restrict__ cur,
                                                      int* __restrict__ col_s,
                                                      int* __restrict__ pos_of_e, int E) {
    int i = blockIdx.x * blockDim.x + threadIdx.x;
    int stride = gridDim.x * blockDim.x;
    for (; i < E; i += stride) {
        int r = row[i];
        int p = atomicAdd(&cur[r], 1);
        col_s[p] = col[i];
        pos_of_e[i] = p;
    }
}

// ---------------- per-node squared norms ----------------

__global__ __launch_bounds__(256) void sqn_kernel(const float* __restrict__ x,
                                                  float* __restrict__ sqn, int n) {
    int wid = (blockIdx.x * blockDim.x + threadIdx.x) >> 6;
    int lane = threadIdx.x & 63;
    if (wid >= n) return;
    float v0 = x[(size_t)wid * DF + lane];
    float v1 = x[(size_t)wid * DF + 64 + lane];
    float s = v0 * v0 + v1 * v1;
    for (int off = 32; off; off >>= 1) s += __shfl_xor(s, off);
    if (lane == 0) sqn[wid] = s;
}

// ---------------- edge weights ----------------
// layer 1: both cosine and euclid from the same dot products on x
__global__ __launch_bounds__(256) void edgew1_kernel(const float* __restrict__ x,
                                                     const float* __restrict__ sqn,
                                                     const int* __restrict__ row,
                                                     const int* __restrict__ col,
                                                     const int* __restrict__ pos_of_e,
                                                     float* __restrict__ wcos,
                                                     float* __restrict__ weuc, int E) {
    int gid = blockIdx.x * blockDim.x + threadIdx.x;
    int g = gid >> 4;   // 16 lanes per edge
    int sub = gid & 15;
    int ngroups = (gridDim.x * blockDim.x) >> 4;
    for (int e = g; e < E; e += ngroups) {
        int r = row[e], c = col[e];
        const float4* xr = (const float4*)x + (size_t)r * 32;
        const float4* xc = (const float4*)x + (size_t)c * 32;
        float4 a0 = xr[sub], a1 = xr[sub + 16];
        float4 b0 = xc[sub], b1 = xc[sub + 16];
        float d = a0.x * b0.x + a0.y * b0.y + a0.z * b0.z + a0.w * b0.w
                + a1.x * b1.x + a1.y * b1.y + a1.z * b1.z + a1.w * b1.w;
        for (int off = 8; off; off >>= 1) d += __shfl_xor(d, off);
        if (sub == 0) {
            float na = sqn[r], nb = sqn[c];
            float cw = d / fmaxf(sqrtf(na * nb), 1e-8f);
            float ew = sqrtf(fmaxf(na + nb - 2.f * d, 0.f) + 1e-12f);
            int p = pos_of_e[e];
            wcos[p] = cw;
            weuc[p] = ew;
        }
    }
}

// layer 2: single metric (0 = cosine, 1 = euclid)
template <int METRIC>
__global__ __launch_bounds__(256) void edgew2_kernel(const float* __restrict__ x,
                                                     const float* __restrict__ sqn,
                                                     const int* __restrict__ row,
                                                     const int* __restrict__ col,
                                                     const int* __restrict__ pos_of_e,
                                                     float* __restrict__ wout, int E) {
    int gid = blockIdx.x * blockDim.x + threadIdx.x;
    int g = gid >> 4;
    int sub = gid & 15;
    int ngroups = (gridDim.x * blockDim.x) >> 4;
    for (int e = g; e < E; e += ngroups) {
        int r = row[e], c = col[e];
        const float4* xr = (const float4*)x + (size_t)r * 32;
        const float4* xc = (const float4*)x + (size_t)c * 32;
        float4 a0 = xr[sub], a1 = xr[sub + 16];
        float4 b0 = xc[sub], b1 = xc[sub + 16];
        float d = a0.x * b0.x + a0.y * b0.y + a0.z * b0.z + a0.w * b0.w
                + a1.x * b1.x + a1.y * b1.y + a1.z * b1.z + a1.w * b1.w;
        for (int off = 8; off; off >>= 1) d += __shfl_xor(d, off);
        if (sub == 0) {
            float na = sqn[r], nb = sqn[c];
            float w;
            if (METRIC == 0)
                w = d / fmaxf(sqrtf(na * nb), 1e-8f);
            else
                w = sqrtf(fmaxf(na + nb - 2.f * d, 0.f) + 1e-12f);
            wout[pos_of_e[e]] = w;
        }
    }
}

// ---------------- degree / dis ----------------

__global__ __launch_bounds__(256) void deg_kernel(const float* __restrict__ ws,
                                                  const int* __restrict__ row_ptr,
                                                  float* __restrict__ dis, int n) {
    int wid = (blockIdx.x * blockDim.x + threadIdx.x) >> 6;
    int lane = threadIdx.x & 63;
    if (wid >= n) return;
    int s = row_ptr[wid], e = row_ptr[wid + 1];
    float acc = 0.f;
    for (int p = s + lane; p < e; p += 64) acc += ws[p];
    for (int off = 32; off; off >>= 1) acc += __shfl_xor(acc, off);
    float deg = 1.f + acc;  // self loop weight 1
    float di = (deg > 0.f) ? rsqrtf(fmaxf(deg, 1e-12f)) : 0.f;
    if (lane == 0) dis[wid] = di;
}

// ---------------- dense matmul h = xin @ W  (N x 128 @ 128 x 128) ----------------
// one wave computes 4 rows
__global__ __launch_bounds__(256) void mm_kernel(const float* __restrict__ xin,
                                                 const float* __restrict__ W,
                                                 float* __restrict__ h, int n) {
    int wid = (blockIdx.x * blockDim.x + threadIdx.x) >> 6;
    int lane = threadIdx.x & 63;
    int i0 = wid * 4;
    if (i0 >= n) return;
    float v0[4], v1[4];
#pragma unroll
    for (int r = 0; r < 4; ++r) {
        int i = i0 + r;
        if (i < n) {
            v0[r] = xin[(size_t)i * DF + lane];
            v1[r] = xin[(size_t)i * DF + 64 + lane];
        } else {
            v0[r] = 0.f; v1[r] = 0.f;
        }
    }
    float acc0[4] = {0.f, 0.f, 0.f, 0.f};
    float acc1[4] = {0.f, 0.f, 0.f, 0.f};
#pragma unroll 4
    for (int k = 0; k < 64; ++k) {
        float w0 = W[k * DF + lane];
        float w1 = W[k * DF + 64 + lane];
#pragma unroll
        for (int r = 0; r < 4; ++r) {
            float a = __shfl(v0[r], k);
            acc0[r] = fmaf(a, w0, acc0[r]);
            acc1[r] = fmaf(a, w1, acc1[r]);
        }
    }
#pragma unroll 4
    for (int k = 0; k < 64; ++k) {
        float w0 = W[(k + 64) * DF + lane];
        float w1 = W[(k + 64) * DF + 64 + lane];
#pragma unroll
        for (int r = 0; r < 4; ++r) {
            float a = __shfl(v1[r], k);
            acc0[r] = fmaf(a, w0, acc0[r]);
            acc1[r] = fmaf(a, w1, acc1[r]);
        }
    }
#pragma unroll
    for (int r = 0; r < 4; ++r) {
        int i = i0 + r;
        if (i < n) {
            h[(size_t)i * DF + lane] = acc0[r];
            h[(size_t)i * DF + 64 + lane] = acc1[r];
        }
    }
}

// ---------------- SpMM: out[i] = dis[i]*(dis[i]*h[i] + sum_e w*dis[c]*h[c]) + b ----------------
// one wave per target node
__global__ __launch_bounds__(256) void spmm_kernel(const float* __restrict__ h,
                                                   const float* __restrict__ ws,
                                                   const int* __restrict__ col_s,
                                                   const float* __restrict__ dis,
                                                   const int* __restrict__ row_ptr,
                                                   const float* __restrict__ bias,
                                                   float* __restrict__ xout,
                                                   float* __restrict__ sqn_out,
                                                   int n, int do_relu) {
    int wid = (blockIdx.x * blockDim.x + threadIdx.x) >> 6;
    int lane = threadIdx.x & 63;
    if (wid >= n) return;
    float di = dis[wid];
    const float* hrow = h + (size_t)wid * DF;
    float acc0 = di * hrow[lane];       // self-loop term (dis_i factored out)
    float acc1 = di * hrow[64 + lane];
    int s = row_ptr[wid], en = row_ptr[wid + 1];
    for (int base = s; base < en; base += 64) {
        int m = en - base;
        if (m > 64) m = 64;
        int c = 0;
        float ce = 0.f;
        if (lane < m) {
            c = col_s[base + lane];
            ce = ws[base + lane] * dis[c];
        }
        for (int j = 0; j < m; ++j) {
            int cj = __shfl(c, j);
            float cej = __shfl(ce, j);
            const float* hc = h + (size_t)cj * DF;
            acc0 = fmaf(cej, hc[lane], acc0);
            acc1 = fmaf(cej, hc[64 + lane], acc1);
        }
    }
    float o0 = di * acc0 + bias[lane];
    float o1 = di * acc1 + bias[64 + lane];
    if (do_relu) {
        o0 = fmaxf(o0, 0.f);
        o1 = fmaxf(o1, 0.f);
    }
    xout[(size_t)wid * DF + lane] = o0;
    xout[(size_t)wid * DF + 64 + lane] = o1;
    if (sqn_out) {
        float s2 = o0 * o0 + o1 * o1;
        for (int off = 32; off; off >>= 1) s2 += __shfl_xor(s2, off);
        if (lane == 0) sqn_out[wid] = s2;
    }
}

// ---------------- semantic attention fusion ----------------
__global__ __launch_bounds__(256) void attn_kernel(const float* __restrict__ x1,
                                                   const float* __restrict__ x2,
                                                   const float* __restrict__ A1,
                                                   const float* __restrict__ ab1,
                                                   const float* __restrict__ A2,
                                                   float* __restrict__ out, int n) {
    __shared__ float sA1[DF * HATT];
    __shared__ float sA2[HATT];
    __shared__ float sab[HATT];
    int tid = threadIdx.x;
    for (int i = tid; i < DF * HATT; i += 256) sA1[i] = A1[i];
    if (tid < HATT) {
        sA2[tid] = A2[tid];
        sab[tid] = ab1[tid];
    }
    __syncthreads();
    int lane = tid & 63;
    int wib = tid >> 6;
    int wid = blockIdx.x * 4 + wib;
    int nw = gridDim.x * 4;
    for (int i = wid; i < n; i += nw) {
        float u0 = x1[(size_t)i * DF + lane], u1 = x1[(size_t)i * DF + 64 + lane];
        float v0 = x2[(size_t)i * DF + lane], v1 = x2[(size_t)i * DF + 64 + lane];
        float acc1 = 0.f, acc2 = 0.f;  // lane = hidden unit h
#pragma unroll 4
        for (int d = 0; d < 64; ++d) {
            float w = sA1[d * HATT + lane];
            acc1 = fmaf(__shfl(u0, d), w, acc1);
            acc2 = fmaf(__shfl(v0, d), w, acc2);
        }
#pragma unroll 4
        for (int d = 0; d < 64; ++d) {
            float w = sA1[(d + 64) * HATT + lane];
            acc1 = fmaf(__shfl(u1, d), w, acc1);
            acc2 = fmaf(__shfl(v1, d), w, acc2);
        }
        float t1 = tanhf(acc1 + sab[lane]) * sA2[lane];
        float t2 = tanhf(acc2 + sab[lane]) * sA2[lane];
        for (int off = 32; off; off >>= 1) {
            t1 += __shfl_xor(t1, off);
            t2 += __shfl_xor(t2, off);
        }
        float mx = fmaxf(t1, t2);
        float e1 = expf(t1 - mx), e2 = expf(t2 - mx);
        float inv = 1.f / (e1 + e2);
        float be1 = e1 * inv, be2 = e2 * inv;
        out[(size_t)i * DF + lane] = be1 * u0 + be2 * v0;
        out[(size_t)i * DF + 64 + lane] = be1 * u1 + be2 * v1;
    }
}

// ---------------- launch ----------------

extern "C" void kernel_launch(void* const* d_in, const int* in_sizes, int n_in,
                              void* d_out, int out_size, void* d_ws, size_t ws_size,
                              hipStream_t stream) {
    const float* x  = (const float*)d_in[0];
    const int* row  = (const int*)d_in[1];
    const int* col  = (const int*)d_in[2];
    const float* W1 = (const float*)d_in[3];
    const float* b1 = (const float*)d_in[4];
    const float* W2 = (const float*)d_in[5];
    const float* b2 = (const float*)d_in[6];
    const float* A1 = (const float*)d_in[7];
    const float* ab1= (const float*)d_in[8];
    const float* A2 = (const float*)d_in[9];
    const int N = in_sizes[0] / DF;
    const int E = in_sizes[1];
    float* out = (float*)d_out;

    // workspace layout
    char* p = (char*)d_ws;
    auto alloc_f = [&](size_t cnt) -> float* {
        float* r = (float*)p;
        p += ((cnt * 4 + 255) / 256) * 256;
        return r;
    };
    auto alloc_i = [&](size_t cnt) -> int* {
        int* r = (int*)p;
        p += ((cnt * 4 + 255) / 256) * 256;
        return r;
    };
    float* h    = alloc_f((size_t)N * DF);
    float* x1   = alloc_f((size_t)N * DF);
    float* x2   = alloc_f((size_t)N * DF);
    float* wsA  = alloc_f(E);
    float* wsB  = alloc_f(E);
    float* dis  = alloc_f(N);
    float* sqnx = alloc_f(N);
    float* sqn1 = alloc_f(N);
    float* sqn2 = alloc_f(N);
    int* cnt    = alloc_i(N);
    int* rowptr = alloc_i(N + 1);
    int* cur    = alloc_i(N);
    int* col_s  = alloc_i(E);
    int* pose   = alloc_i(E);
    (void)ws_size; (void)n_in; (void)out_size;

    const int nodeBlocks = divup(N * 64, 256);      // wave per node
    const int mmBlocks   = divup(divup(N, 4), 4);   // wave per 4 rows

    // graph prep (shared by all 4 GCN calls)
    hipMemsetAsync(cnt, 0, (size_t)N * 4, stream);
    hist_kernel<<<1024, 256, 0, stream>>>(row, cnt, E);
    sqn_kernel<<<nodeBlocks, 256, 0, stream>>>(x, sqnx, N);
    scan_kernel<<<1, 1024, 0, stream>>>(cnt, rowptr, cur, N);
    scatter_kernel<<<1024, 256, 0, stream>>>(row, col, cur, col_s, pose, E);

    // layer-1 edge weights (cos + euclid share dot products on x)
    edgew1_kernel<<<4096, 256, 0, stream>>>(x, sqnx, row, col, pose, wsA, wsB, E);

    // shared layer-1 transform
    mm_kernel<<<mmBlocks, 256, 0, stream>>>(x, W1, h, N);

    // cosine branch layer 1 -> x1 (relu) + sqn1
    deg_kernel<<<nodeBlocks, 256, 0, stream>>>(wsA, rowptr, dis, N);
    spmm_kernel<<<nodeBlocks, 256, 0, stream>>>(h, wsA, col_s, dis, rowptr, b1, x1, sqn1, N, 1);

    // euclid branch layer 1 -> x2 (relu) + sqn2
    deg_kernel<<<nodeBlocks, 256, 0, stream>>>(wsB, rowptr, dis, N);
    spmm_kernel<<<nodeBlocks, 256, 0, stream>>>(h, wsB, col_s, dis, rowptr, b1, x2, sqn2, N, 1);

    // cosine branch layer 2 (no relu), overwrite x1
    edgew2_kernel<0><<<4096, 256, 0, stream>>>(x1, sqn1, row, col, pose, wsA, E);
    deg_kernel<<<nodeBlocks, 256, 0, stream>>>(wsA, rowptr, dis, N);
    mm_kernel<<<mmBlocks, 256, 0, stream>>>(x1, W2, h, N);
    spmm_kernel<<<nodeBlocks, 256, 0, stream>>>(h, wsA, col_s, dis, rowptr, b2, x1, nullptr, N, 0);

    // euclid branch layer 2 (no relu), overwrite x2
    edgew2_kernel<1><<<4096, 256, 0, stream>>>(x2, sqn2, row, col, pose, wsB, E);
    deg_kernel<<<nodeBlocks, 256, 0, stream>>>(wsB, rowptr, dis, N);
    mm_kernel<<<mmBlocks, 256, 0, stream>>>(x2, W2, h, N);
    spmm_kernel<<<nodeBlocks, 256, 0, stream>>>(h, wsB, col_s, dis, rowptr, b2, x2, nullptr, N, 0);

    // semantic attention fusion -> out
    attn_kernel<<<divup(N, 4), 256, 0, stream>>>(x1, x2, A1, ab1, A2, out, N);
}